// Round 13
// baseline (594.439 us; speedup 1.0000x reference)
//
#include <hip/hip_runtime.h>

#define BATCH 4
#define CH    128
#define NPTS  2000
#define KNN   9
#define NHEAD 4
#define HD    32
#define NHALF 1000

typedef unsigned short u16;
typedef __attribute__((ext_vector_type(4))) float f32x4;
typedef __attribute__((ext_vector_type(8))) short bf16x8;

// ---- workspace layout (float offsets) ---- total 6,437,504 floats (same as baseline)
#define OFF_XT    0          // (B,N,128) transposed x fp32 ; later attn O0 partial
#define OFF_YT    1024000    // (B,N,128) transposed y ; later attn O1 partial -> ADD
#define OFF_PT    2048000    // P edge ; later V^T bf16 splits ; then TT half
#define OFF_QT    3072000    // Q edge ; later K bf16 splits ; then TT half
#define OFF_AGG   4096000    // knn split-C partials ; then edge-conv output m1 (B,N,128)
#define OFF_MH    5120000    // X bf16 splits (knn) ; Q bf16 splits ; later wmh output
#define OFF_MISC  6144000
#define OFF_W1SUM (OFF_MISC)            // [o][c] BN-folded
#define OFF_W1B   (OFF_MISC+16384)      // [o][c]
#define OFF_W2T   (OFF_MISC+32768)      // [o][c] scaled w2
#define OFF_ML0   (OFF_MISC+49152)      // attn split-0 (m,l): 4*4*2000*2 = 64,000 floats
#define OFF_WC1T  (OFF_MISC+114688)     // [o][c] scaled wc1 (256x256)
#define OFF_B1F   (OFF_MISC+212992)
#define OFF_B2F   (OFF_MISC+213120)
#define OFF_BC1F  (OFF_MISC+213248)
#define OFF_XX    (OFF_MISC+213504)     // B*N sums of squares ; later attn split-1 (m,l)
#define OFF_IDX   (OFF_MISC+221504)     // B*N*9 ints (dead after edgeconv)

// ---------------- bf16 helpers (RNE) ----------------
__device__ __forceinline__ void bsplit(float v, u16& hi, u16& lo)
{
    unsigned u = __float_as_uint(v);
    unsigned h16 = (u + 0x7fffu + ((u >> 16) & 1u)) >> 16;
    float hf = __uint_as_float(h16 << 16);
    float lf = v - hf;
    unsigned ul = __float_as_uint(lf);
    hi = (u16)h16;
    lo = (u16)((ul + 0x7fffu + ((ul >> 16) & 1u)) >> 16);
}

__device__ __forceinline__ f32x4 mfma16(bf16x8 a, bf16x8 b, f32x4 c)
{
    return __builtin_amdgcn_mfma_f32_16x16x32_bf16(a, b, c, 0, 0, 0);
}

// ---------------- weight prep: BN folding, [o][c] layouts ----------------
__global__ __launch_bounds__(256) void prep_kernel(
    const float* __restrict__ w1, const float* __restrict__ b1,
    const float* __restrict__ g1, const float* __restrict__ be1,
    const float* __restrict__ w2, const float* __restrict__ b2,
    const float* __restrict__ g2, const float* __restrict__ be2,
    const float* __restrict__ wc1, const float* __restrict__ bc1,
    const float* __restrict__ cg, const float* __restrict__ cbe,
    float* __restrict__ ws)
{
    int id = blockIdx.x * 256 + threadIdx.x;   // 65536 threads
    const float rs = rsqrtf(1.f + 1e-5f);
    if (id < 16384) {
        int o = id >> 7;
        int c = id & 127;
        float s1 = g1[o] * rs;
        ws[OFF_W1SUM + id] = (w1[o*256 + c] + w1[o*256 + 128 + c]) * s1;
        ws[OFF_W1B   + id] = w1[o*256 + 128 + c] * s1;
        ws[OFF_W2T   + id] = w2[id] * (g2[o] * rs);
    }
    {   // wc1 (256,256) already [o][c]; scale rows
        int o = id >> 8;
        ws[OFF_WC1T + id] = wc1[id] * (cg[o] * rs);
    }
    if (id < 128) {
        float s1 = g1[id] * rs, s2 = g2[id] * rs;
        ws[OFF_B1F + id] = b1[id]*s1 + be1[id];
        ws[OFF_B2F + id] = b2[id]*s2 + be2[id];
    }
    if (id < 256) {
        ws[OFF_BC1F + id] = bc1[id]*(cg[id]*rs) + cbe[id];
    }
}

// ---------------- transpose (B,C,N)->(B,N,C) + xx + bf16 split (fused) ----------------
__global__ __launch_bounds__(128) void transpose_split_kernel(
    const float* __restrict__ src, float* __restrict__ dst, float* __restrict__ xx,
    u16* __restrict__ H, u16* __restrict__ L)
{
    int blk = blockIdx.x; int b = blk / NPTS, n = blk % NPTS;
    int c = threadIdx.x;
    float v = src[((size_t)b*CH + c)*NPTS + n];
    size_t di = ((size_t)b*NPTS + n)*CH + c;
    dst[di] = v;
    u16 hi, lo;
    bsplit(v, hi, lo);
    H[di] = hi; L[di] = lo;
    __shared__ float red[128];
    red[c] = v*v;
    __syncthreads();
    for (int s = 64; s > 0; s >>= 1) { if (c < s) red[c] += red[c+s]; __syncthreads(); }
    if (c == 0) xx[b*NPTS + n] = red[0];
}

// ---------------- plain transpose (B,C,N)->(B,N,C) ----------------
__global__ __launch_bounds__(128) void transpose_kernel(
    const float* __restrict__ src, float* __restrict__ dst)
{
    int blk = blockIdx.x; int b = blk / NPTS, n = blk % NPTS;
    int c = threadIdx.x;
    dst[((size_t)b*NPTS + n)*CH + c] = src[((size_t)b*CH + c)*NPTS + n];
}

// ---------------- KNN: MFMA distance GEMM, candidate-split x2 ----------------
// grid (125, B, 2): blockIdx.z = candidate half (tiles 0..62 / 63..124).
// Inner loop byte-identical to the measured-best r12 form (split-4, single
// accumulator chain). Each block emits its sorted per-query top-9 partial
// (vals+ids) to global; knn_merge combines the two sorted lists.
__global__ __launch_bounds__(512) void knn8_kernel(
    const u16* __restrict__ XH, const u16* __restrict__ XL,
    const float* __restrict__ xx, float* __restrict__ PV, int* __restrict__ PI)
{
    __shared__ float woutv[8][16][9];
    __shared__ int   wouti[8][16][9];
    int b = blockIdx.y;
    int half = blockIdx.z;
    int q0 = blockIdx.x * 16;          // 125 blocks exactly
    int tid = threadIdx.x;
    int wave = tid >> 6, lane = tid & 63;
    int lg = lane >> 4, lr = lane & 15;
    const float* xxb = xx + (size_t)b*NPTS;
    int tstart = half ? 63 : 0;
    int tend   = half ? 125 : 63;

    size_t qb = ((size_t)b*NPTS + q0 + lr)*128 + lg*8;
    bf16x8 qh[4], ql[4];
#pragma unroll
    for (int ch = 0; ch < 4; ch++) {
        qh[ch] = *(const bf16x8*)&XH[qb + ch*32];
        ql[ch] = *(const bf16x8*)&XL[qb + ch*32];
    }

    float vals[4][9]; int ids[4][9];
    float vmin[4]; int amin[4];
#pragma unroll
    for (int j = 0; j < 4; j++) {
#pragma unroll
        for (int k = 0; k < 9; k++) { vals[j][k] = -3.4e38f; ids[j][k] = -1; }
        vmin[j] = -3.4e38f; amin[j] = 0;
    }

    for (int t = tstart + wave; t < tend; t += 8) {
        size_t kb = ((size_t)b*NPTS + t*16 + lr)*128 + lg*8;
        bf16x8 fh[4], fl[4];
#pragma unroll
        for (int ch = 0; ch < 4; ch++) {
            fh[ch] = *(const bf16x8*)&XH[kb + ch*32];
            fl[ch] = *(const bf16x8*)&XL[kb + ch*32];
        }
        float xv = xxb[t*16 + lr];
        f32x4 acc = {0.f,0.f,0.f,0.f};
#pragma unroll
        for (int ch = 0; ch < 4; ch++) {
            acc = mfma16(qh[ch], fh[ch], acc);
            acc = mfma16(qh[ch], fl[ch], acc);
            acc = mfma16(ql[ch], fh[ch], acc);
            acc = mfma16(ql[ch], fl[ch], acc);
        }
        int cand = t*16 + lr;
#pragma unroll
        for (int j = 0; j < 4; j++) {
            float s = 2.f*acc[j] - xv;
            if (s > vmin[j]) {
#pragma unroll
                for (int k = 0; k < 9; k++) {
                    bool sel = (k == amin[j]);
                    vals[j][k] = sel ? s    : vals[j][k];
                    ids[j][k]  = sel ? cand : ids[j][k];
                }
                vmin[j] = vals[j][0]; amin[j] = 0;
#pragma unroll
                for (int k = 1; k < 9; k++) {
                    bool lt = vals[j][k] < vmin[j];
                    vmin[j] = lt ? vals[j][k] : vmin[j];
                    amin[j] = lt ? k : amin[j];
                }
            }
        }
    }

#pragma unroll
    for (int j = 0; j < 4; j++) {
        unsigned used = 0;
        for (int r = 0; r < 9; r++) {
            float bv = -3.4e38f; int bm = -1;
#pragma unroll
            for (int k = 0; k < 9; k++) {
                bool ok = !(used & (1u << k)) && (vals[j][k] > bv);
                bv = ok ? vals[j][k] : bv;
                bm = ok ? ids[j][k]  : bm;
            }
            float v = bv; int mi = bm;
#pragma unroll
            for (int off = 1; off < 16; off <<= 1) {
                float ov = __shfl_xor(v, off);
                int  omi = __shfl_xor(mi, off);
                if (ov > v || (ov == v && omi >= 0 && omi < mi)) { v = ov; mi = omi; }
            }
#pragma unroll
            for (int k = 0; k < 9; k++) {
                if (ids[j][k] == mi) used |= (1u << k);
            }
            if (lr == 0) { woutv[wave][lg*4+j][r] = v; wouti[wave][lg*4+j][r] = mi; }
        }
    }
    __syncthreads();

    if (tid < 16) {
        float v0 = woutv[0][tid][0], v1 = woutv[1][tid][0], v2 = woutv[2][tid][0], v3 = woutv[3][tid][0];
        float v4 = woutv[4][tid][0], v5 = woutv[5][tid][0], v6 = woutv[6][tid][0], v7 = woutv[7][tid][0];
        int   i0 = wouti[0][tid][0], i1 = wouti[1][tid][0], i2 = wouti[2][tid][0], i3 = wouti[3][tid][0];
        int   i4 = wouti[4][tid][0], i5 = wouti[5][tid][0], i6 = wouti[6][tid][0], i7 = wouti[7][tid][0];
        int   p0 = 1, p1 = 1, p2 = 1, p3 = 1, p4 = 1, p5 = 1, p6 = 1, p7 = 1;
        size_t po = (((size_t)half*BATCH + b)*NPTS + q0 + tid)*9;
        for (int r = 0; r < 9; r++) {
            int w = 0; float bv = v0; int bi = i0;
            if (v1 > bv || (v1 == bv && i1 < bi)) { w = 1; bv = v1; bi = i1; }
            if (v2 > bv || (v2 == bv && i2 < bi)) { w = 2; bv = v2; bi = i2; }
            if (v3 > bv || (v3 == bv && i3 < bi)) { w = 3; bv = v3; bi = i3; }
            if (v4 > bv || (v4 == bv && i4 < bi)) { w = 4; bv = v4; bi = i4; }
            if (v5 > bv || (v5 == bv && i5 < bi)) { w = 5; bv = v5; bi = i5; }
            if (v6 > bv || (v6 == bv && i6 < bi)) { w = 6; bv = v6; bi = i6; }
            if (v7 > bv || (v7 == bv && i7 < bi)) { w = 7; bv = v7; bi = i7; }
            PV[po + r] = bv; PI[po + r] = bi;
            if (w == 0)      { v0 = (p0 < 9) ? woutv[0][tid][p0] : -3.4e38f; i0 = (p0 < 9) ? wouti[0][tid][p0] : 0x7fffffff; p0++; }
            else if (w == 1) { v1 = (p1 < 9) ? woutv[1][tid][p1] : -3.4e38f; i1 = (p1 < 9) ? wouti[1][tid][p1] : 0x7fffffff; p1++; }
            else if (w == 2) { v2 = (p2 < 9) ? woutv[2][tid][p2] : -3.4e38f; i2 = (p2 < 9) ? wouti[2][tid][p2] : 0x7fffffff; p2++; }
            else if (w == 3) { v3 = (p3 < 9) ? woutv[3][tid][p3] : -3.4e38f; i3 = (p3 < 9) ? wouti[3][tid][p3] : 0x7fffffff; p3++; }
            else if (w == 4) { v4 = (p4 < 9) ? woutv[4][tid][p4] : -3.4e38f; i4 = (p4 < 9) ? wouti[4][tid][p4] : 0x7fffffff; p4++; }
            else if (w == 5) { v5 = (p5 < 9) ? woutv[5][tid][p5] : -3.4e38f; i5 = (p5 < 9) ? wouti[5][tid][p5] : 0x7fffffff; p5++; }
            else if (w == 6) { v6 = (p6 < 9) ? woutv[6][tid][p6] : -3.4e38f; i6 = (p6 < 9) ? wouti[6][tid][p6] : 0x7fffffff; p6++; }
            else             { v7 = (p7 < 9) ? woutv[7][tid][p7] : -3.4e38f; i7 = (p7 < 9) ? wouti[7][tid][p7] : 0x7fffffff; p7++; }
        }
    }
}

// ---------------- knn candidate-half merge: two sorted 9-lists -> top-9 ----------------
__global__ __launch_bounds__(256) void knn_merge_kernel(
    const float* __restrict__ PV, const int* __restrict__ PI, int* __restrict__ idxOut)
{
    int q = blockIdx.x * 256 + threadIdx.x;   // over B*NPTS = 8000
    if (q >= BATCH*NPTS) return;
    const float* v0p = PV + (size_t)q*9;
    const int*   i0p = PI + (size_t)q*9;
    const float* v1p = PV + ((size_t)BATCH*NPTS + q)*9;
    const int*   i1p = PI + ((size_t)BATCH*NPTS + q)*9;
    int p0 = 0, p1 = 0;
    int* op = idxOut + (size_t)q*9;
#pragma unroll
    for (int r = 0; r < 9; r++) {
        float a = v0p[p0], bb = v1p[p1];
        int ia = i0p[p0], ib = i1p[p1];
        bool takeB = (bb > a) || (bb == a && ib < ia);
        op[r] = takeB ? ib : ia;
        if (takeB) p1++; else p0++;
    }
}

// ---------------- dual GEMM (fp32 outputs), 8 rows/block, weights [o][c] ----------------
__global__ __launch_bounds__(128) void gemm_dual_kernel(
    const float* __restrict__ In, const float* __restrict__ Wa, const float* __restrict__ Wb,
    const float* __restrict__ ba, const float* __restrict__ bb,
    float* __restrict__ OutA, float* __restrict__ OutB)
{
    __shared__ float in_lds[8][128];
    int row0 = blockIdx.x * 8, tid = threadIdx.x;
    const float* src = In + (size_t)row0 * 128;
    for (int i = tid; i < 1024; i += 128) ((float*)in_lds)[i] = src[i];
    __syncthreads();
    float accA[8], accB[8];
    float bA = ba ? ba[tid] : 0.f, bB = bb ? bb[tid] : 0.f;
#pragma unroll
    for (int j = 0; j < 8; j++) { accA[j] = bA; accB[j] = bB; }
    const float4* wra = (const float4*)(Wa + (size_t)tid * 128);
    const float4* wrb = (const float4*)(Wb + (size_t)tid * 128);
#pragma unroll 4
    for (int c4 = 0; c4 < 32; c4++) {
        float4 wa = wra[c4], wb = wrb[c4];
#pragma unroll
        for (int j = 0; j < 8; j++) {
            float4 xi = ((const float4*)&in_lds[j][0])[c4];
            accA[j] += xi.x*wa.x + xi.y*wa.y + xi.z*wa.z + xi.w*wa.w;
            accB[j] += xi.x*wb.x + xi.y*wb.y + xi.z*wb.z + xi.w*wb.w;
        }
    }
#pragma unroll
    for (int j = 0; j < 8; j++) {
        OutA[(size_t)(row0 + j)*128 + tid] = accA[j];
        OutB[(size_t)(row0 + j)*128 + tid] = accB[j];
    }
}

// ---------------- k/v GEMM fused with bf16 split (K row-major, V transposed) ----------------
__global__ __launch_bounds__(128) void gemm_kv_kernel(
    const float* __restrict__ In, const float* __restrict__ Wa, const float* __restrict__ Wb,
    const float* __restrict__ ba, const float* __restrict__ bb,
    u16* __restrict__ KHo, u16* __restrict__ KLo,
    u16* __restrict__ VTHo, u16* __restrict__ VTLo)
{
    __shared__ float in_lds[8][128];
    int row0 = blockIdx.x * 8, tid = threadIdx.x;
    const float* src = In + (size_t)row0 * 128;
    for (int i = tid; i < 1024; i += 128) ((float*)in_lds)[i] = src[i];
    __syncthreads();
    float accA[8], accB[8];
    float bA = ba[tid], bB = bb[tid];
#pragma unroll
    for (int j = 0; j < 8; j++) { accA[j] = bA; accB[j] = bB; }
    const float4* wra = (const float4*)(Wa + (size_t)tid * 128);
    const float4* wrb = (const float4*)(Wb + (size_t)tid * 128);
#pragma unroll 4
    for (int c4 = 0; c4 < 32; c4++) {
        float4 wa = wra[c4], wb = wrb[c4];
#pragma unroll
        for (int j = 0; j < 8; j++) {
            float4 xi = ((const float4*)&in_lds[j][0])[c4];
            accA[j] += xi.x*wa.x + xi.y*wa.y + xi.z*wa.z + xi.w*wa.w;
            accB[j] += xi.x*wb.x + xi.y*wb.y + xi.z*wb.z + xi.w*wb.w;
        }
    }
    int b = row0 / NPTS, n0 = row0 % NPTS;   // 2000%8==0: block within one batch
#pragma unroll
    for (int j = 0; j < 8; j++) {
        u16 hh, ll;
        bsplit(accA[j], hh, ll);
        size_t ko = (size_t)(row0 + j)*128 + tid;
        KHo[ko] = hh; KLo[ko] = ll;
        bsplit(accB[j], hh, ll);
        size_t vo = ((size_t)b*128 + tid)*NPTS + n0 + j;
        VTHo[vo] = hh; VTLo[vo] = ll;
    }
}

// ---------------- q GEMM fused with bf16 split ----------------
__global__ __launch_bounds__(128) void gemm_q_kernel(
    const float* __restrict__ In, const float* __restrict__ Wt, const float* __restrict__ bias,
    u16* __restrict__ H, u16* __restrict__ L)
{
    __shared__ float in_lds[8][128];
    int row0 = blockIdx.x * 8, tid = threadIdx.x;
    const float* src = In + (size_t)row0 * 128;
    for (int i = tid; i < 1024; i += 128) ((float*)in_lds)[i] = src[i];
    __syncthreads();
    float acc[8];
    float b = bias[tid];
#pragma unroll
    for (int j = 0; j < 8; j++) acc[j] = b;
    const float4* wrow = (const float4*)(Wt + (size_t)tid * 128);
#pragma unroll 4
    for (int c4 = 0; c4 < 32; c4++) {
        float4 w = wrow[c4];
#pragma unroll
        for (int j = 0; j < 8; j++) {
            float4 xi = ((const float4*)&in_lds[j][0])[c4];
            acc[j] += xi.x*w.x + xi.y*w.y + xi.z*w.z + xi.w*w.w;
        }
    }
#pragma unroll
    for (int j = 0; j < 8; j++) {
        u16 hh, ll;
        bsplit(acc[j], hh, ll);
        size_t o = (size_t)(row0 + j)*128 + tid;
        H[o] = hh; L[o] = ll;
    }
}

// ---------------- generic GEMM, 8 rows/block, weights [o][c] ----------------
template<int CIN, int COUT, bool RELU, bool TRANSOUT, bool HASRES, bool CONCAT>
__global__ __launch_bounds__(COUT) void gemmT_kernel(
    const float* __restrict__ In, const float* __restrict__ In2,
    const float* __restrict__ Wt, const float* __restrict__ bias,
    const float* __restrict__ Res, float* __restrict__ Out)
{
    __shared__ float in_lds[8][CIN];
    int row0 = blockIdx.x * 8, tid = threadIdx.x;
    if (!CONCAT) {
        const float* src = In + (size_t)row0 * CIN;
        for (int i = tid; i < 8*CIN; i += COUT) ((float*)in_lds)[i] = src[i];
    } else {
        for (int i = tid; i < 8*128; i += COUT) {
            int j = i >> 7, c = i & 127;
            in_lds[j][c]       = In [(size_t)(row0 + j)*128 + c];
            in_lds[j][128 + c] = In2[(size_t)(row0 + j)*128 + c];
        }
    }
    __syncthreads();
    float acc[8];
    float b = bias ? bias[tid] : 0.f;
#pragma unroll
    for (int j = 0; j < 8; j++) acc[j] = b;
    const float4* wrow = (const float4*)(Wt + (size_t)tid * CIN);
#pragma unroll 4
    for (int c4 = 0; c4 < CIN/4; c4++) {
        float4 w = wrow[c4];
#pragma unroll
        for (int j = 0; j < 8; j++) {
            float4 xi = ((const float4*)&in_lds[j][0])[c4];
            acc[j] += xi.x*w.x + xi.y*w.y + xi.z*w.z + xi.w*w.w;
        }
    }
#pragma unroll
    for (int j = 0; j < 8; j++) {
        float v = acc[j];
        if (RELU) v = fmaxf(v, 0.f);
        size_t row = row0 + j;
        if (HASRES) v += Res[row*COUT + tid];
        if (!TRANSOUT) {
            Out[row*COUT + tid] = v;
        } else {
            int b_ = (int)(row / NPTS), n_ = (int)(row % NPTS);
            Out[((size_t)b_*COUT + tid)*NPTS + n_] = v;
        }
    }
}

// ---------------- edge conv: gather + conv2(+bn+relu) + max over k ----------------
__global__ __launch_bounds__(128) void edgeconv_kernel(
    const float* __restrict__ Pt, const float* __restrict__ Qt,
    const int* __restrict__ idx, const float* __restrict__ W2t,
    const float* __restrict__ b2f, float* __restrict__ Agg)
{
    int blk = blockIdx.x; int b = blk / NPTS, n = blk % NPTS;
    int o = threadIdx.x;
    __shared__ float r[9][128];
    __shared__ int mk[9];
    if (o < 9) mk[o] = idx[((size_t)b*NPTS + n)*KNN + o];
    __syncthreads();
    float p = Pt[((size_t)b*NPTS + n)*128 + o];
#pragma unroll
    for (int k = 0; k < 9; k++) {
        float q = Qt[((size_t)b*NPTS + mk[k])*128 + o];
        r[k][o] = fmaxf(p - q, 0.f);   // relu(bn1(conv1)) folded
    }
    __syncthreads();
    float acc[9];
#pragma unroll
    for (int k = 0; k < 9; k++) acc[k] = 0.f;
    const float4* w2row = (const float4*)(W2t + (size_t)o * 128);
#pragma unroll 2
    for (int c4 = 0; c4 < 32; c4++) {
        float4 w = w2row[c4];
#pragma unroll
        for (int k = 0; k < 9; k++) {
            float4 rv = ((const float4*)&r[k][0])[c4];
            acc[k] += rv.x*w.x + rv.y*w.y + rv.z*w.z + rv.w*w.w;
        }
    }
    float bb = b2f[o];
    float vmax = -3.4e38f;
#pragma unroll
    for (int k = 0; k < 9; k++) vmax = fmaxf(vmax, fmaxf(acc[k] + bb, 0.f));
    Agg[((size_t)b*NPTS + n)*128 + o] = vmax;
}

// ---------------- MFMA flash attention, split-K x2 (32-key inner) ----------------
#define PSTR 72
__global__ __launch_bounds__(256) void attn_mfma_kernel(
    const u16* __restrict__ QH, const u16* __restrict__ QL,
    const u16* __restrict__ KH, const u16* __restrict__ KL,
    const u16* __restrict__ VTH, const u16* __restrict__ VTL,
    float* __restrict__ O0, float* __restrict__ O1,
    float* __restrict__ ML0, float* __restrict__ ML1)
{
    __shared__ alignas(16) u16 Ph[4][16][PSTR];
    __shared__ alignas(16) u16 Pl[4][16][PSTR];
    int b = blockIdx.z, h = blockIdx.y;
    int split = blockIdx.x & 1, qt = blockIdx.x >> 1;
    int wave = threadIdx.x >> 6, lane = threadIdx.x & 63;
    int lg = lane >> 4, lr = lane & 15;
    int q0 = qt * 64 + wave * 16;
    if (q0 >= NPTS) return;   // no barriers in kernel, tail-exit safe
    int kstart = split * NHALF, kend = kstart + NHALF;
    float* Op = split ? O1 : O0;
    float* ml = split ? ML1 : ML0;

    size_t qb = ((size_t)b*NPTS + q0 + lr)*128 + h*32 + lg*8;
    const bf16x8 qh = *(const bf16x8*)&QH[qb];
    const bf16x8 ql = *(const bf16x8*)&QL[qb];

    f32x4 o0 = {0.f,0.f,0.f,0.f}, o1 = {0.f,0.f,0.f,0.f};
    float mrun[4], lsum[4];
#pragma unroll
    for (int r = 0; r < 4; r++) { mrun[r] = -3.0e38f; lsum[r] = 0.f; }
    const float sc = 0.17677669529663687f;  // 1/sqrt(32)
    int shsrc = ((lr >> 2) << 4) | (lr & 3);

    for (int ks = kstart; ks < kend; ks += 32) {
        // ---- QK^T for two 16-key tiles (both boundary-masked) ----
        int k0i = ks + lr;      bool vk0 = k0i < kend; if (k0i > kend-1) k0i = kend-1;
        int k1i = ks + 16 + lr; bool vk1 = k1i < kend; if (k1i > kend-1) k1i = kend-1;
        size_t kb0 = ((size_t)b*NPTS + k0i)*128 + h*32 + lg*8;
        size_t kb1 = ((size_t)b*NPTS + k1i)*128 + h*32 + lg*8;
        bf16x8 k0h = *(const bf16x8*)&KH[kb0];
        bf16x8 k0l = *(const bf16x8*)&KL[kb0];
        bf16x8 k1h = *(const bf16x8*)&KH[kb1];
        bf16x8 k1l = *(const bf16x8*)&KL[kb1];
        f32x4 s0 = {0.f,0.f,0.f,0.f}, s1 = {0.f,0.f,0.f,0.f};
        s0 = mfma16(qh, k0h, s0);
        s0 = mfma16(qh, k0l, s0);
        s0 = mfma16(ql, k0h, s0);
        s1 = mfma16(qh, k1h, s1);
        s1 = mfma16(qh, k1l, s1);
        s1 = mfma16(ql, k1h, s1);
        float mx[4];
#pragma unroll
        for (int r = 0; r < 4; r++) {
            float a  = vk0 ? s0[r]*sc : -3.0e38f;
            float a2 = vk1 ? s1[r]*sc : -3.0e38f;
            s0[r] = a; s1[r] = a2;
            mx[r] = fmaxf(a, a2);
        }
#pragma unroll
        for (int off = 1; off < 16; off <<= 1) {
#pragma unroll
            for (int r = 0; r < 4; r++) mx[r] = fmaxf(mx[r], __shfl_xor(mx[r], off));
        }
        // ---- online softmax ----
        float e0[4], e1[4], rsu[4], sca[4];
#pragma unroll
        for (int r = 0; r < 4; r++) {
            float mn = fmaxf(mrun[r], mx[r]);
            sca[r] = __expf(mrun[r] - mn);
            mrun[r] = mn;
            e0[r] = __expf(s0[r] - mn);
            e1[r] = __expf(s1[r] - mn);
            rsu[r] = e0[r] + e1[r];
        }
#pragma unroll
        for (int off = 1; off < 16; off <<= 1) {
#pragma unroll
            for (int r = 0; r < 4; r++) rsu[r] += __shfl_xor(rsu[r], off);
        }
#pragma unroll
        for (int r = 0; r < 4; r++) lsum[r] = lsum[r]*sca[r] + rsu[r];
        // ---- stage P (split hi/lo) in wave-private LDS ----
#pragma unroll
        for (int r = 0; r < 4; r++) {
            u16 h0, w0, h1, w1;
            bsplit(e0[r], h0, w0);
            bsplit(e1[r], h1, w1);
            int qr = lg*4 + r;
            Ph[wave][qr][lr]      = h0;
            Pl[wave][qr][lr]      = w0;
            Ph[wave][qr][16 + lr] = h1;
            Pl[wave][qr][16 + lr] = w1;
        }
        // ---- rescale O ----
        float scsel = (lr & 2) ? ((lr & 1) ? sca[3] : sca[2])
                               : ((lr & 1) ? sca[1] : sca[0]);
        float osc = __shfl(scsel, shsrc);
#pragma unroll
        for (int r = 0; r < 4; r++) { o0[r] *= osc; o1[r] *= osc; }
        // ---- O^T += V^T · P^T ----
        int cb = ks + lg*8; if (cb > kend-8) cb = kend-8;   // clamped; P rows there are 0
        bf16x8 pbh = *(const bf16x8*)&Ph[wave][lr][lg*8];
        bf16x8 pbl = *(const bf16x8*)&Pl[wave][lr][lg*8];
        size_t vb = ((size_t)b*128 + h*32 + lr)*NPTS + cb;
        bf16x8 v0h = *(const bf16x8*)&VTH[vb];
        bf16x8 v0l = *(const bf16x8*)&VTL[vb];
        bf16x8 v1h = *(const bf16x8*)&VTH[vb + 16*NPTS];
        bf16x8 v1l = *(const bf16x8*)&VTL[vb + 16*NPTS];
        o0 = mfma16(v0h, pbh, o0);
        o0 = mfma16(v0l, pbh, o0);
        o0 = mfma16(v0h, pbl, o0);
        o1 = mfma16(v1h, pbh, o1);
        o1 = mfma16(v1l, pbh, o1);
        o1 = mfma16(v1h, pbl, o1);
    }
    // ---- write partials: unnormalized O + (m,l) per q row ----
    if (lr == 0) {
#pragma unroll
        for (int r = 0; r < 4; r++) {
            size_t mo = (((size_t)b*NHEAD + h)*NPTS + q0 + lg*4 + r)*2;
            ml[mo]   = mrun[r];
            ml[mo+1] = lsum[r];
        }
    }
    int q = q0 + lr;
    size_t ob = ((size_t)b*NPTS + q)*128 + h*32;
#pragma unroll
    for (int r = 0; r < 4; r++) {
        Op[ob + lg*4 + r]      = o0[r];
        Op[ob + 16 + lg*4 + r] = o1[r];
    }
}

// ---------------- split-K merge: ADD = (O0*w0 + O1*w1) / (l0*w0 + l1*w1) ----------------
__global__ __launch_bounds__(256) void attn_merge_kernel(
    const float* __restrict__ O0, const float* __restrict__ ML0,
    const float* __restrict__ ML1, float* __restrict__ O1 /* in-out -> ADD */)
{
    int id = blockIdx.x * 256 + threadIdx.x;   // over B*N*128 = 1,024,000
    int c = id & 127;
    int q = (id >> 7) % NPTS;
    int b = id / (NPTS * 128);
    int h = c >> 5;
    size_t mo = (((size_t)b*NHEAD + h)*NPTS + q)*2;
    float m0 = ML0[mo], l0 = ML0[mo+1];
    float m1 = ML1[mo], l1 = ML1[mo+1];
    float M = fmaxf(m0, m1);
    float w0 = __expf(m0 - M), w1 = __expf(m1 - M);
    float inv = 1.f / (l0*w0 + l1*w1);
    O1[id] = (O0[id]*w0 + O1[id]*w1) * inv;
}

// ---------------- launcher ----------------
extern "C" void kernel_launch(void* const* d_in, const int* in_sizes, int n_in,
                              void* d_out, int out_size, void* d_ws, size_t ws_size,
                              hipStream_t stream)
{
    const float* x    = (const float*)d_in[0];
    const float* y    = (const float*)d_in[1];
    const float* w1   = (const float*)d_in[2];
    const float* b1   = (const float*)d_in[3];
    const float* g1   = (const float*)d_in[4];
    const float* be1  = (const float*)d_in[5];
    const float* w2   = (const float*)d_in[6];
    const float* b2   = (const float*)d_in[7];
    const float* g2   = (const float*)d_in[8];
    const float* be2  = (const float*)d_in[9];
    const float* wq   = (const float*)d_in[10];
    const float* bq   = (const float*)d_in[11];
    const float* wk   = (const float*)d_in[12];
    const float* bk   = (const float*)d_in[13];
    const float* wv   = (const float*)d_in[14];
    const float* bv   = (const float*)d_in[15];
    const float* wmh  = (const float*)d_in[16];
    const float* bmh  = (const float*)d_in[17];
    const float* wc1  = (const float*)d_in[18];
    const float* bc1  = (const float*)d_in[19];
    const float* cg   = (const float*)d_in[20];
    const float* cbe  = (const float*)d_in[21];
    const float* wc2  = (const float*)d_in[22];
    const float* bc2  = (const float*)d_in[23];
    float* ws = (float*)d_ws;
    float* out = (float*)d_out;

    float* XT  = ws + OFF_XT;
    float* YT  = ws + OFF_YT;
    float* PT  = ws + OFF_PT;
    float* QT  = ws + OFF_QT;
    float* AGG = ws + OFF_AGG;
    float* MH  = ws + OFF_MH;
    float* XX  = ws + OFF_XX;
    int*   IDX = (int*)(ws + OFF_IDX);
    float* O0s = XT;   // attn split-0 partial (XT dead after gemm_dual)
    float* O1s = YT;   // attn split-1 partial -> merged in place -> ADD
    float* ADD = YT;
    float* ML0 = ws + OFF_ML0;   // unused weight gap
    float* ML1 = ws + OFF_XX;    // XX+IDX dead after knn/edgeconv
    float* TT  = PT;   // 8000x256 spans PT+QT (after attn frees splits)
    // knn candidate-split partials in AGG region (free until edgeconv):
    float* KPV = AGG;                         // 2*8000*9 = 144,000 floats
    int*   KPI = (int*)(AGG + 144000);        // 144,000 ints
    const int SPE = BATCH*NPTS*CH;          // 1,024,000 u16 per array
    u16* XHs = (u16*)MH;  u16* XLs = XHs + SPE;   // X splits for knn (dead after knn)
    u16* QHs = (u16*)MH;  u16* QLs = QHs + SPE;   // Q splits (overwrite X splits)
    u16* KHs = (u16*)QT;  u16* KLs = KHs + SPE;   // QT region (after edgeconv)
    u16* VTH = (u16*)PT;  u16* VTL = VTH + SPE;   // PT region (after edgeconv)

    prep_kernel<<<256, 256, 0, stream>>>(w1, b1, g1, be1, w2, b2, g2, be2,
                                         wc1, bc1, cg, cbe, ws);
    transpose_split_kernel<<<BATCH*NPTS, 128, 0, stream>>>(x, XT, XX, XHs, XLs);
    transpose_kernel<<<BATCH*NPTS, 128, 0, stream>>>(y, YT);
    knn8_kernel<<<dim3(NPTS/16, BATCH, 2), 512, 0, stream>>>(XHs, XLs, XX, KPV, KPI);
    knn_merge_kernel<<<(BATCH*NPTS + 255)/256, 256, 0, stream>>>(KPV, KPI, IDX);
    gemm_dual_kernel<<<BATCH*NPTS/8, 128, 0, stream>>>(XT, ws + OFF_W1SUM, ws + OFF_W1B,
                                                       ws + OFF_B1F, nullptr, PT, QT);
    edgeconv_kernel<<<BATCH*NPTS, 128, 0, stream>>>(PT, QT, IDX, ws + OFF_W2T,
                                                    ws + OFF_B2F, AGG);
    gemm_q_kernel<<<BATCH*NPTS/8, 128, 0, stream>>>(AGG, wq, bq, QHs, QLs);
    gemm_kv_kernel<<<BATCH*NPTS/8, 128, 0, stream>>>(YT, wk, wv, bk, bv,
                                                     KHs, KLs, VTH, VTL);
    attn_mfma_kernel<<<dim3(64, NHEAD, BATCH), 256, 0, stream>>>(
        QHs, QLs, KHs, KLs, VTH, VTL, O0s, O1s, ML0, ML1);
    attn_merge_kernel<<<BATCH*NPTS*CH/256, 256, 0, stream>>>(O0s, ML0, ML1, O1s);
    gemmT_kernel<128,128,false,false,false,false><<<BATCH*NPTS/8, 128, 0, stream>>>(
        ADD, nullptr, wmh, bmh, nullptr, MH);
    gemmT_kernel<256,256,true,false,false,true><<<BATCH*NPTS/8, 256, 0, stream>>>(
        AGG, MH, ws + OFF_WC1T, ws + OFF_BC1F, nullptr, TT);
    gemmT_kernel<256,128,false,true,true,false><<<BATCH*NPTS/8, 128, 0, stream>>>(
        TT, nullptr, wc2, bc2, AGG, out);
}

// Round 14
// 529.232 us; speedup vs baseline: 1.1232x; 1.1232x over previous
//
#include <hip/hip_runtime.h>

#define BATCH 4
#define CH    128
#define NPTS  2000
#define KNN   9
#define NHEAD 4
#define HD    32
#define NHALF 1000

typedef unsigned short u16;
typedef __attribute__((ext_vector_type(4))) float f32x4;
typedef __attribute__((ext_vector_type(8))) short bf16x8;

// ---- workspace layout (float offsets) ---- total 6,437,504 floats (same as baseline)
#define OFF_XT    0          // (B,N,128) transposed x fp32 ; later attn O0 partial
#define OFF_YT    1024000    // (B,N,128) transposed y ; later attn O1 partial
#define OFF_PT    2048000    // P edge ; later V^T bf16 splits ; then TT half
#define OFF_QT    3072000    // Q edge ; later K bf16 splits ; then TT half
#define OFF_AGG   4096000    // edge-conv output m1 (B,N,128)
#define OFF_MH    5120000    // X bf16 splits (knn) ; Q bf16 splits ; later wmh output
#define OFF_MISC  6144000
#define OFF_W1SUM (OFF_MISC)            // [o][c] BN-folded
#define OFF_W1B   (OFF_MISC+16384)      // [o][c]
#define OFF_W2T   (OFF_MISC+32768)      // [o][c] scaled w2
#define OFF_ML0   (OFF_MISC+49152)      // attn split-0 (m,l): 4*4*2000*2 = 64,000 floats
#define OFF_WC1T  (OFF_MISC+114688)     // [o][c] scaled wc1 (256x256)
#define OFF_B1F   (OFF_MISC+212992)
#define OFF_B2F   (OFF_MISC+213120)
#define OFF_BC1F  (OFF_MISC+213248)
#define OFF_XX    (OFF_MISC+213504)     // B*N sums of squares ; later attn split-1 (m,l)
#define OFF_IDX   (OFF_MISC+221504)     // B*N*9 ints (dead after edgeconv)

// ---------------- bf16 helpers (RNE) ----------------
__device__ __forceinline__ void bsplit(float v, u16& hi, u16& lo)
{
    unsigned u = __float_as_uint(v);
    unsigned h16 = (u + 0x7fffu + ((u >> 16) & 1u)) >> 16;
    float hf = __uint_as_float(h16 << 16);
    float lf = v - hf;
    unsigned ul = __float_as_uint(lf);
    hi = (u16)h16;
    lo = (u16)((ul + 0x7fffu + ((ul >> 16) & 1u)) >> 16);
}

__device__ __forceinline__ f32x4 mfma16(bf16x8 a, bf16x8 b, f32x4 c)
{
    return __builtin_amdgcn_mfma_f32_16x16x32_bf16(a, b, c, 0, 0, 0);
}

// ---------------- weight prep: BN folding, [o][c] layouts ----------------
__global__ __launch_bounds__(256) void prep_kernel(
    const float* __restrict__ w1, const float* __restrict__ b1,
    const float* __restrict__ g1, const float* __restrict__ be1,
    const float* __restrict__ w2, const float* __restrict__ b2,
    const float* __restrict__ g2, const float* __restrict__ be2,
    const float* __restrict__ wc1, const float* __restrict__ bc1,
    const float* __restrict__ cg, const float* __restrict__ cbe,
    float* __restrict__ ws)
{
    int id = blockIdx.x * 256 + threadIdx.x;   // 65536 threads
    const float rs = rsqrtf(1.f + 1e-5f);
    if (id < 16384) {
        int o = id >> 7;
        int c = id & 127;
        float s1 = g1[o] * rs;
        ws[OFF_W1SUM + id] = (w1[o*256 + c] + w1[o*256 + 128 + c]) * s1;
        ws[OFF_W1B   + id] = w1[o*256 + 128 + c] * s1;
        ws[OFF_W2T   + id] = w2[id] * (g2[o] * rs);
    }
    {   // wc1 (256,256) already [o][c]; scale rows
        int o = id >> 8;
        ws[OFF_WC1T + id] = wc1[id] * (cg[o] * rs);
    }
    if (id < 128) {
        float s1 = g1[id] * rs, s2 = g2[id] * rs;
        ws[OFF_B1F + id] = b1[id]*s1 + be1[id];
        ws[OFF_B2F + id] = b2[id]*s2 + be2[id];
    }
    if (id < 256) {
        ws[OFF_BC1F + id] = bc1[id]*(cg[id]*rs) + cbe[id];
    }
}

// ---------------- fused transposes: x (with xx + bf16 split) and y ----------------
__global__ __launch_bounds__(128) void transpose_fused_kernel(
    const float* __restrict__ x, const float* __restrict__ y,
    float* __restrict__ XT, float* __restrict__ YT, float* __restrict__ xx,
    u16* __restrict__ H, u16* __restrict__ L)
{
    int blk = blockIdx.x;
    int c = threadIdx.x;
    if (blk < BATCH*NPTS) {
        int b = blk / NPTS, n = blk % NPTS;
        float v = x[((size_t)b*CH + c)*NPTS + n];
        size_t di = ((size_t)b*NPTS + n)*CH + c;
        XT[di] = v;
        u16 hi, lo;
        bsplit(v, hi, lo);
        H[di] = hi; L[di] = lo;
        __shared__ float red[128];
        red[c] = v*v;
        __syncthreads();
        for (int s = 64; s > 0; s >>= 1) { if (c < s) red[c] += red[c+s]; __syncthreads(); }
        if (c == 0) xx[b*NPTS + n] = red[0];
    } else {
        int blk2 = blk - BATCH*NPTS;
        int b = blk2 / NPTS, n = blk2 % NPTS;
        YT[((size_t)b*NPTS + n)*CH + c] = y[((size_t)b*CH + c)*NPTS + n];
    }
}

// ---------------- KNN: MFMA distance GEMM + register top-9, 8 waves ----------------
// Inner loop and merge in their simple forms — measured-best at 127.7 us.
// (Indep-acc, explicit prefetch, and candidate-split all regressed.)
__global__ __launch_bounds__(512) void knn8_kernel(
    const u16* __restrict__ XH, const u16* __restrict__ XL,
    const float* __restrict__ xx, int* __restrict__ idxOut)
{
    __shared__ float woutv[8][16][9];
    __shared__ int   wouti[8][16][9];
    int b = blockIdx.y;
    int q0 = blockIdx.x * 16;          // 125 blocks exactly
    int tid = threadIdx.x;
    int wave = tid >> 6, lane = tid & 63;
    int lg = lane >> 4, lr = lane & 15;
    const float* xxb = xx + (size_t)b*NPTS;

    size_t qb = ((size_t)b*NPTS + q0 + lr)*128 + lg*8;
    bf16x8 qh[4], ql[4];
#pragma unroll
    for (int ch = 0; ch < 4; ch++) {
        qh[ch] = *(const bf16x8*)&XH[qb + ch*32];
        ql[ch] = *(const bf16x8*)&XL[qb + ch*32];
    }

    float vals[4][9]; int ids[4][9];
    float vmin[4]; int amin[4];
#pragma unroll
    for (int j = 0; j < 4; j++) {
#pragma unroll
        for (int k = 0; k < 9; k++) { vals[j][k] = -3.4e38f; ids[j][k] = -1; }
        vmin[j] = -3.4e38f; amin[j] = 0;
    }

    for (int t = wave; t < 125; t += 8) {
        size_t kb = ((size_t)b*NPTS + t*16 + lr)*128 + lg*8;
        bf16x8 fh[4], fl[4];
#pragma unroll
        for (int ch = 0; ch < 4; ch++) {
            fh[ch] = *(const bf16x8*)&XH[kb + ch*32];
            fl[ch] = *(const bf16x8*)&XL[kb + ch*32];
        }
        float xv = xxb[t*16 + lr];
        f32x4 acc = {0.f,0.f,0.f,0.f};
#pragma unroll
        for (int ch = 0; ch < 4; ch++) {
            acc = mfma16(qh[ch], fh[ch], acc);
            acc = mfma16(qh[ch], fl[ch], acc);
            acc = mfma16(ql[ch], fh[ch], acc);
            acc = mfma16(ql[ch], fl[ch], acc);
        }
        int cand = t*16 + lr;
#pragma unroll
        for (int j = 0; j < 4; j++) {
            float s = 2.f*acc[j] - xv;
            if (s > vmin[j]) {
#pragma unroll
                for (int k = 0; k < 9; k++) {
                    bool sel = (k == amin[j]);
                    vals[j][k] = sel ? s    : vals[j][k];
                    ids[j][k]  = sel ? cand : ids[j][k];
                }
                vmin[j] = vals[j][0]; amin[j] = 0;
#pragma unroll
                for (int k = 1; k < 9; k++) {
                    bool lt = vals[j][k] < vmin[j];
                    vmin[j] = lt ? vals[j][k] : vmin[j];
                    amin[j] = lt ? k : amin[j];
                }
            }
        }
    }

#pragma unroll
    for (int j = 0; j < 4; j++) {
        unsigned used = 0;
        for (int r = 0; r < 9; r++) {
            float bv = -3.4e38f; int bm = -1;
#pragma unroll
            for (int k = 0; k < 9; k++) {
                bool ok = !(used & (1u << k)) && (vals[j][k] > bv);
                bv = ok ? vals[j][k] : bv;
                bm = ok ? ids[j][k]  : bm;
            }
            float v = bv; int mi = bm;
#pragma unroll
            for (int off = 1; off < 16; off <<= 1) {
                float ov = __shfl_xor(v, off);
                int  omi = __shfl_xor(mi, off);
                if (ov > v || (ov == v && omi >= 0 && omi < mi)) { v = ov; mi = omi; }
            }
#pragma unroll
            for (int k = 0; k < 9; k++) {
                if (ids[j][k] == mi) used |= (1u << k);
            }
            if (lr == 0) { woutv[wave][lg*4+j][r] = v; wouti[wave][lg*4+j][r] = mi; }
        }
    }
    __syncthreads();

    if (tid < 16) {
        float v0 = woutv[0][tid][0], v1 = woutv[1][tid][0], v2 = woutv[2][tid][0], v3 = woutv[3][tid][0];
        float v4 = woutv[4][tid][0], v5 = woutv[5][tid][0], v6 = woutv[6][tid][0], v7 = woutv[7][tid][0];
        int   i0 = wouti[0][tid][0], i1 = wouti[1][tid][0], i2 = wouti[2][tid][0], i3 = wouti[3][tid][0];
        int   i4 = wouti[4][tid][0], i5 = wouti[5][tid][0], i6 = wouti[6][tid][0], i7 = wouti[7][tid][0];
        int   p0 = 1, p1 = 1, p2 = 1, p3 = 1, p4 = 1, p5 = 1, p6 = 1, p7 = 1;
        int* op = idxOut + ((size_t)b*NPTS + q0 + tid)*KNN;
        for (int r = 0; r < 9; r++) {
            int w = 0; float bv = v0; int bi = i0;
            if (v1 > bv || (v1 == bv && i1 < bi)) { w = 1; bv = v1; bi = i1; }
            if (v2 > bv || (v2 == bv && i2 < bi)) { w = 2; bv = v2; bi = i2; }
            if (v3 > bv || (v3 == bv && i3 < bi)) { w = 3; bv = v3; bi = i3; }
            if (v4 > bv || (v4 == bv && i4 < bi)) { w = 4; bv = v4; bi = i4; }
            if (v5 > bv || (v5 == bv && i5 < bi)) { w = 5; bv = v5; bi = i5; }
            if (v6 > bv || (v6 == bv && i6 < bi)) { w = 6; bv = v6; bi = i6; }
            if (v7 > bv || (v7 == bv && i7 < bi)) { w = 7; bv = v7; bi = i7; }
            op[r] = bi;
            if (w == 0)      { v0 = (p0 < 9) ? woutv[0][tid][p0] : -3.4e38f; i0 = (p0 < 9) ? wouti[0][tid][p0] : 0x7fffffff; p0++; }
            else if (w == 1) { v1 = (p1 < 9) ? woutv[1][tid][p1] : -3.4e38f; i1 = (p1 < 9) ? wouti[1][tid][p1] : 0x7fffffff; p1++; }
            else if (w == 2) { v2 = (p2 < 9) ? woutv[2][tid][p2] : -3.4e38f; i2 = (p2 < 9) ? wouti[2][tid][p2] : 0x7fffffff; p2++; }
            else if (w == 3) { v3 = (p3 < 9) ? woutv[3][tid][p3] : -3.4e38f; i3 = (p3 < 9) ? wouti[3][tid][p3] : 0x7fffffff; p3++; }
            else if (w == 4) { v4 = (p4 < 9) ? woutv[4][tid][p4] : -3.4e38f; i4 = (p4 < 9) ? wouti[4][tid][p4] : 0x7fffffff; p4++; }
            else if (w == 5) { v5 = (p5 < 9) ? woutv[5][tid][p5] : -3.4e38f; i5 = (p5 < 9) ? wouti[5][tid][p5] : 0x7fffffff; p5++; }
            else if (w == 6) { v6 = (p6 < 9) ? woutv[6][tid][p6] : -3.4e38f; i6 = (p6 < 9) ? wouti[6][tid][p6] : 0x7fffffff; p6++; }
            else             { v7 = (p7 < 9) ? woutv[7][tid][p7] : -3.4e38f; i7 = (p7 < 9) ? wouti[7][tid][p7] : 0x7fffffff; p7++; }
        }
    }
}

// ---------------- dual GEMM (fp32 outputs), 8 rows/block, weights [o][c] ----------------
__global__ __launch_bounds__(128) void gemm_dual_kernel(
    const float* __restrict__ In, const float* __restrict__ Wa, const float* __restrict__ Wb,
    const float* __restrict__ ba, const float* __restrict__ bb,
    float* __restrict__ OutA, float* __restrict__ OutB)
{
    __shared__ float in_lds[8][128];
    int row0 = blockIdx.x * 8, tid = threadIdx.x;
    const float* src = In + (size_t)row0 * 128;
    for (int i = tid; i < 1024; i += 128) ((float*)in_lds)[i] = src[i];
    __syncthreads();
    float accA[8], accB[8];
    float bA = ba ? ba[tid] : 0.f, bB = bb ? bb[tid] : 0.f;
#pragma unroll
    for (int j = 0; j < 8; j++) { accA[j] = bA; accB[j] = bB; }
    const float4* wra = (const float4*)(Wa + (size_t)tid * 128);
    const float4* wrb = (const float4*)(Wb + (size_t)tid * 128);
#pragma unroll 4
    for (int c4 = 0; c4 < 32; c4++) {
        float4 wa = wra[c4], wb = wrb[c4];
#pragma unroll
        for (int j = 0; j < 8; j++) {
            float4 xi = ((const float4*)&in_lds[j][0])[c4];
            accA[j] += xi.x*wa.x + xi.y*wa.y + xi.z*wa.z + xi.w*wa.w;
            accB[j] += xi.x*wb.x + xi.y*wb.y + xi.z*wb.z + xi.w*wb.w;
        }
    }
#pragma unroll
    for (int j = 0; j < 8; j++) {
        OutA[(size_t)(row0 + j)*128 + tid] = accA[j];
        OutB[(size_t)(row0 + j)*128 + tid] = accB[j];
    }
}

// ---------------- fused q + k/v GEMMs with bf16 split outputs ----------------
// grid 2*BATCH*NPTS/8: blocks [0,1000) = q path (In=AGG), [1000,2000) = kv path (In=YT).
__global__ __launch_bounds__(128) void gemm_qkv_kernel(
    const float* __restrict__ AGG, const float* __restrict__ YT,
    const float* __restrict__ wq, const float* __restrict__ bq,
    const float* __restrict__ wk, const float* __restrict__ bk,
    const float* __restrict__ wv, const float* __restrict__ bv,
    u16* __restrict__ QHo, u16* __restrict__ QLo,
    u16* __restrict__ KHo, u16* __restrict__ KLo,
    u16* __restrict__ VTHo, u16* __restrict__ VTLo)
{
    __shared__ float in_lds[8][128];
    const int nb = BATCH*NPTS/8;
    bool isQ = blockIdx.x < nb;
    int row0 = (isQ ? blockIdx.x : blockIdx.x - nb) * 8;
    int tid = threadIdx.x;
    const float* src = (isQ ? AGG : YT) + (size_t)row0 * 128;
    for (int i = tid; i < 1024; i += 128) ((float*)in_lds)[i] = src[i];
    __syncthreads();
    if (isQ) {
        float acc[8];
        float b = bq[tid];
#pragma unroll
        for (int j = 0; j < 8; j++) acc[j] = b;
        const float4* wrow = (const float4*)(wq + (size_t)tid * 128);
#pragma unroll 4
        for (int c4 = 0; c4 < 32; c4++) {
            float4 w = wrow[c4];
#pragma unroll
            for (int j = 0; j < 8; j++) {
                float4 xi = ((const float4*)&in_lds[j][0])[c4];
                acc[j] += xi.x*w.x + xi.y*w.y + xi.z*w.z + xi.w*w.w;
            }
        }
#pragma unroll
        for (int j = 0; j < 8; j++) {
            u16 hh, ll;
            bsplit(acc[j], hh, ll);
            size_t o = (size_t)(row0 + j)*128 + tid;
            QHo[o] = hh; QLo[o] = ll;
        }
    } else {
        float accA[8], accB[8];
        float bA = bk[tid], bB = bv[tid];
#pragma unroll
        for (int j = 0; j < 8; j++) { accA[j] = bA; accB[j] = bB; }
        const float4* wra = (const float4*)(wk + (size_t)tid * 128);
        const float4* wrb = (const float4*)(wv + (size_t)tid * 128);
#pragma unroll 4
        for (int c4 = 0; c4 < 32; c4++) {
            float4 wa = wra[c4], wb = wrb[c4];
#pragma unroll
            for (int j = 0; j < 8; j++) {
                float4 xi = ((const float4*)&in_lds[j][0])[c4];
                accA[j] += xi.x*wa.x + xi.y*wa.y + xi.z*wa.z + xi.w*wa.w;
                accB[j] += xi.x*wb.x + xi.y*wb.y + xi.z*wb.z + xi.w*wb.w;
            }
        }
        int b = row0 / NPTS, n0 = row0 % NPTS;
#pragma unroll
        for (int j = 0; j < 8; j++) {
            u16 hh, ll;
            bsplit(accA[j], hh, ll);
            size_t ko = (size_t)(row0 + j)*128 + tid;
            KHo[ko] = hh; KLo[ko] = ll;
            bsplit(accB[j], hh, ll);
            size_t vo = ((size_t)b*128 + tid)*NPTS + n0 + j;
            VTHo[vo] = hh; VTLo[vo] = ll;
        }
    }
}

// ---------------- wmh GEMM with attn split-K merge fused into the load ----------------
__global__ __launch_bounds__(128) void gemm_mh_kernel(
    const float* __restrict__ O0, const float* __restrict__ O1,
    const float* __restrict__ ML0, const float* __restrict__ ML1,
    const float* __restrict__ Wt, const float* __restrict__ bias,
    float* __restrict__ Out)
{
    __shared__ float in_lds[8][128];
    int row0 = blockIdx.x * 8, tid = threadIdx.x;
    // stage merged ADD rows: thread tid handles column tid of 8 rows
    {
        int c = tid;
        int h_ = c >> 5;
#pragma unroll
        for (int j = 0; j < 8; j++) {
            int row = row0 + j;
            int b_ = row / NPTS, q_ = row % NPTS;
            size_t mo = (((size_t)b_*NHEAD + h_)*NPTS + q_)*2;
            float m0 = ML0[mo], l0 = ML0[mo+1];
            float m1 = ML1[mo], l1 = ML1[mo+1];
            float M = fmaxf(m0, m1);
            float w0 = __expf(m0 - M), w1 = __expf(m1 - M);
            float inv = 1.f / (l0*w0 + l1*w1);
            size_t oi = (size_t)row*128 + c;
            in_lds[j][c] = (O0[oi]*w0 + O1[oi]*w1) * inv;
        }
    }
    __syncthreads();
    float acc[8];
    float b = bias[tid];
#pragma unroll
    for (int j = 0; j < 8; j++) acc[j] = b;
    const float4* wrow = (const float4*)(Wt + (size_t)tid * 128);
#pragma unroll 4
    for (int c4 = 0; c4 < 32; c4++) {
        float4 w = wrow[c4];
#pragma unroll
        for (int j = 0; j < 8; j++) {
            float4 xi = ((const float4*)&in_lds[j][0])[c4];
            acc[j] += xi.x*w.x + xi.y*w.y + xi.z*w.z + xi.w*w.w;
        }
    }
#pragma unroll
    for (int j = 0; j < 8; j++) {
        Out[(size_t)(row0 + j)*128 + tid] = acc[j];
    }
}

// ---------------- generic GEMM, 8 rows/block, weights [o][c] ----------------
template<int CIN, int COUT, bool RELU, bool TRANSOUT, bool HASRES, bool CONCAT>
__global__ __launch_bounds__(COUT) void gemmT_kernel(
    const float* __restrict__ In, const float* __restrict__ In2,
    const float* __restrict__ Wt, const float* __restrict__ bias,
    const float* __restrict__ Res, float* __restrict__ Out)
{
    __shared__ float in_lds[8][CIN];
    int row0 = blockIdx.x * 8, tid = threadIdx.x;
    if (!CONCAT) {
        const float* src = In + (size_t)row0 * CIN;
        for (int i = tid; i < 8*CIN; i += COUT) ((float*)in_lds)[i] = src[i];
    } else {
        for (int i = tid; i < 8*128; i += COUT) {
            int j = i >> 7, c = i & 127;
            in_lds[j][c]       = In [(size_t)(row0 + j)*128 + c];
            in_lds[j][128 + c] = In2[(size_t)(row0 + j)*128 + c];
        }
    }
    __syncthreads();
    float acc[8];
    float b = bias ? bias[tid] : 0.f;
#pragma unroll
    for (int j = 0; j < 8; j++) acc[j] = b;
    const float4* wrow = (const float4*)(Wt + (size_t)tid * CIN);
#pragma unroll 4
    for (int c4 = 0; c4 < CIN/4; c4++) {
        float4 w = wrow[c4];
#pragma unroll
        for (int j = 0; j < 8; j++) {
            float4 xi = ((const float4*)&in_lds[j][0])[c4];
            acc[j] += xi.x*w.x + xi.y*w.y + xi.z*w.z + xi.w*w.w;
        }
    }
#pragma unroll
    for (int j = 0; j < 8; j++) {
        float v = acc[j];
        if (RELU) v = fmaxf(v, 0.f);
        size_t row = row0 + j;
        if (HASRES) v += Res[row*COUT + tid];
        if (!TRANSOUT) {
            Out[row*COUT + tid] = v;
        } else {
            int b_ = (int)(row / NPTS), n_ = (int)(row % NPTS);
            Out[((size_t)b_*COUT + tid)*NPTS + n_] = v;
        }
    }
}

// ---------------- edge conv: gather + conv2(+bn+relu) + max over k ----------------
__global__ __launch_bounds__(128) void edgeconv_kernel(
    const float* __restrict__ Pt, const float* __restrict__ Qt,
    const int* __restrict__ idx, const float* __restrict__ W2t,
    const float* __restrict__ b2f, float* __restrict__ Agg)
{
    int blk = blockIdx.x; int b = blk / NPTS, n = blk % NPTS;
    int o = threadIdx.x;
    __shared__ float r[9][128];
    __shared__ int mk[9];
    if (o < 9) mk[o] = idx[((size_t)b*NPTS + n)*KNN + o];
    __syncthreads();
    float p = Pt[((size_t)b*NPTS + n)*128 + o];
#pragma unroll
    for (int k = 0; k < 9; k++) {
        float q = Qt[((size_t)b*NPTS + mk[k])*128 + o];
        r[k][o] = fmaxf(p - q, 0.f);   // relu(bn1(conv1)) folded
    }
    __syncthreads();
    float acc[9];
#pragma unroll
    for (int k = 0; k < 9; k++) acc[k] = 0.f;
    const float4* w2row = (const float4*)(W2t + (size_t)o * 128);
#pragma unroll 2
    for (int c4 = 0; c4 < 32; c4++) {
        float4 w = w2row[c4];
#pragma unroll
        for (int k = 0; k < 9; k++) {
            float4 rv = ((const float4*)&r[k][0])[c4];
            acc[k] += rv.x*w.x + rv.y*w.y + rv.z*w.z + rv.w*w.w;
        }
    }
    float bb = b2f[o];
    float vmax = -3.4e38f;
#pragma unroll
    for (int k = 0; k < 9; k++) vmax = fmaxf(vmax, fmaxf(acc[k] + bb, 0.f));
    Agg[((size_t)b*NPTS + n)*128 + o] = vmax;
}

// ---------------- MFMA flash attention, split-K x2 (32-key inner) ----------------
#define PSTR 72
__global__ __launch_bounds__(256) void attn_mfma_kernel(
    const u16* __restrict__ QH, const u16* __restrict__ QL,
    const u16* __restrict__ KH, const u16* __restrict__ KL,
    const u16* __restrict__ VTH, const u16* __restrict__ VTL,
    float* __restrict__ O0, float* __restrict__ O1,
    float* __restrict__ ML0, float* __restrict__ ML1)
{
    __shared__ alignas(16) u16 Ph[4][16][PSTR];
    __shared__ alignas(16) u16 Pl[4][16][PSTR];
    int b = blockIdx.z, h = blockIdx.y;
    int split = blockIdx.x & 1, qt = blockIdx.x >> 1;
    int wave = threadIdx.x >> 6, lane = threadIdx.x & 63;
    int lg = lane >> 4, lr = lane & 15;
    int q0 = qt * 64 + wave * 16;
    if (q0 >= NPTS) return;   // no barriers in kernel, tail-exit safe
    int kstart = split * NHALF, kend = kstart + NHALF;
    float* Op = split ? O1 : O0;
    float* ml = split ? ML1 : ML0;

    size_t qb = ((size_t)b*NPTS + q0 + lr)*128 + h*32 + lg*8;
    const bf16x8 qh = *(const bf16x8*)&QH[qb];
    const bf16x8 ql = *(const bf16x8*)&QL[qb];

    f32x4 o0 = {0.f,0.f,0.f,0.f}, o1 = {0.f,0.f,0.f,0.f};
    float mrun[4], lsum[4];
#pragma unroll
    for (int r = 0; r < 4; r++) { mrun[r] = -3.0e38f; lsum[r] = 0.f; }
    const float sc = 0.17677669529663687f;  // 1/sqrt(32)
    int shsrc = ((lr >> 2) << 4) | (lr & 3);

    for (int ks = kstart; ks < kend; ks += 32) {
        // ---- QK^T for two 16-key tiles (both boundary-masked) ----
        int k0i = ks + lr;      bool vk0 = k0i < kend; if (k0i > kend-1) k0i = kend-1;
        int k1i = ks + 16 + lr; bool vk1 = k1i < kend; if (k1i > kend-1) k1i = kend-1;
        size_t kb0 = ((size_t)b*NPTS + k0i)*128 + h*32 + lg*8;
        size_t kb1 = ((size_t)b*NPTS + k1i)*128 + h*32 + lg*8;
        bf16x8 k0h = *(const bf16x8*)&KH[kb0];
        bf16x8 k0l = *(const bf16x8*)&KL[kb0];
        bf16x8 k1h = *(const bf16x8*)&KH[kb1];
        bf16x8 k1l = *(const bf16x8*)&KL[kb1];
        f32x4 s0 = {0.f,0.f,0.f,0.f}, s1 = {0.f,0.f,0.f,0.f};
        s0 = mfma16(qh, k0h, s0);
        s0 = mfma16(qh, k0l, s0);
        s0 = mfma16(ql, k0h, s0);
        s1 = mfma16(qh, k1h, s1);
        s1 = mfma16(qh, k1l, s1);
        s1 = mfma16(ql, k1h, s1);
        float mx[4];
#pragma unroll
        for (int r = 0; r < 4; r++) {
            float a  = vk0 ? s0[r]*sc : -3.0e38f;
            float a2 = vk1 ? s1[r]*sc : -3.0e38f;
            s0[r] = a; s1[r] = a2;
            mx[r] = fmaxf(a, a2);
        }
#pragma unroll
        for (int off = 1; off < 16; off <<= 1) {
#pragma unroll
            for (int r = 0; r < 4; r++) mx[r] = fmaxf(mx[r], __shfl_xor(mx[r], off));
        }
        // ---- online softmax ----
        float e0[4], e1[4], rsu[4], sca[4];
#pragma unroll
        for (int r = 0; r < 4; r++) {
            float mn = fmaxf(mrun[r], mx[r]);
            sca[r] = __expf(mrun[r] - mn);
            mrun[r] = mn;
            e0[r] = __expf(s0[r] - mn);
            e1[r] = __expf(s1[r] - mn);
            rsu[r] = e0[r] + e1[r];
        }
#pragma unroll
        for (int off = 1; off < 16; off <<= 1) {
#pragma unroll
            for (int r = 0; r < 4; r++) rsu[r] += __shfl_xor(rsu[r], off);
        }
#pragma unroll
        for (int r = 0; r < 4; r++) lsum[r] = lsum[r]*sca[r] + rsu[r];
        // ---- stage P (split hi/lo) in wave-private LDS ----
#pragma unroll
        for (int r = 0; r < 4; r++) {
            u16 h0, w0, h1, w1;
            bsplit(e0[r], h0, w0);
            bsplit(e1[r], h1, w1);
            int qr = lg*4 + r;
            Ph[wave][qr][lr]      = h0;
            Pl[wave][qr][lr]      = w0;
            Ph[wave][qr][16 + lr] = h1;
            Pl[wave][qr][16 + lr] = w1;
        }
        // ---- rescale O ----
        float scsel = (lr & 2) ? ((lr & 1) ? sca[3] : sca[2])
                               : ((lr & 1) ? sca[1] : sca[0]);
        float osc = __shfl(scsel, shsrc);
#pragma unroll
        for (int r = 0; r < 4; r++) { o0[r] *= osc; o1[r] *= osc; }
        // ---- O^T += V^T · P^T ----
        int cb = ks + lg*8; if (cb > kend-8) cb = kend-8;   // clamped; P rows there are 0
        bf16x8 pbh = *(const bf16x8*)&Ph[wave][lr][lg*8];
        bf16x8 pbl = *(const bf16x8*)&Pl[wave][lr][lg*8];
        size_t vb = ((size_t)b*128 + h*32 + lr)*NPTS + cb;
        bf16x8 v0h = *(const bf16x8*)&VTH[vb];
        bf16x8 v0l = *(const bf16x8*)&VTL[vb];
        bf16x8 v1h = *(const bf16x8*)&VTH[vb + 16*NPTS];
        bf16x8 v1l = *(const bf16x8*)&VTL[vb + 16*NPTS];
        o0 = mfma16(v0h, pbh, o0);
        o0 = mfma16(v0l, pbh, o0);
        o0 = mfma16(v0h, pbl, o0);
        o1 = mfma16(v1h, pbh, o1);
        o1 = mfma16(v1l, pbh, o1);
        o1 = mfma16(v1h, pbl, o1);
    }
    // ---- write partials: unnormalized O + (m,l) per q row ----
    if (lr == 0) {
#pragma unroll
        for (int r = 0; r < 4; r++) {
            size_t mo = (((size_t)b*NHEAD + h)*NPTS + q0 + lg*4 + r)*2;
            ml[mo]   = mrun[r];
            ml[mo+1] = lsum[r];
        }
    }
    int q = q0 + lr;
    size_t ob = ((size_t)b*NPTS + q)*128 + h*32;
#pragma unroll
    for (int r = 0; r < 4; r++) {
        Op[ob + lg*4 + r]      = o0[r];
        Op[ob + 16 + lg*4 + r] = o1[r];
    }
}

// ---------------- launcher ----------------
extern "C" void kernel_launch(void* const* d_in, const int* in_sizes, int n_in,
                              void* d_out, int out_size, void* d_ws, size_t ws_size,
                              hipStream_t stream)
{
    const float* x    = (const float*)d_in[0];
    const float* y    = (const float*)d_in[1];
    const float* w1   = (const float*)d_in[2];
    const float* b1   = (const float*)d_in[3];
    const float* g1   = (const float*)d_in[4];
    const float* be1  = (const float*)d_in[5];
    const float* w2   = (const float*)d_in[6];
    const float* b2   = (const float*)d_in[7];
    const float* g2   = (const float*)d_in[8];
    const float* be2  = (const float*)d_in[9];
    const float* wq   = (const float*)d_in[10];
    const float* bq   = (const float*)d_in[11];
    const float* wk   = (const float*)d_in[12];
    const float* bk   = (const float*)d_in[13];
    const float* wv   = (const float*)d_in[14];
    const float* bv   = (const float*)d_in[15];
    const float* wmh  = (const float*)d_in[16];
    const float* bmh  = (const float*)d_in[17];
    const float* wc1  = (const float*)d_in[18];
    const float* bc1  = (const float*)d_in[19];
    const float* cg   = (const float*)d_in[20];
    const float* cbe  = (const float*)d_in[21];
    const float* wc2  = (const float*)d_in[22];
    const float* bc2  = (const float*)d_in[23];
    float* ws = (float*)d_ws;
    float* out = (float*)d_out;

    float* XT  = ws + OFF_XT;
    float* YT  = ws + OFF_YT;
    float* PT  = ws + OFF_PT;
    float* QT  = ws + OFF_QT;
    float* AGG = ws + OFF_AGG;
    float* MH  = ws + OFF_MH;
    float* XX  = ws + OFF_XX;
    int*   IDX = (int*)(ws + OFF_IDX);
    float* O0s = XT;   // attn split-0 partial (XT dead after gemm_dual)
    float* O1s = YT;   // attn split-1 partial (merged inline by gemm_mh)
    float* ML0 = ws + OFF_ML0;   // unused weight gap
    float* ML1 = ws + OFF_XX;    // XX+IDX dead after knn/edgeconv
    float* TT  = PT;   // 8000x256 spans PT+QT (after attn frees splits)
    const int SPE = BATCH*NPTS*CH;          // 1,024,000 u16 per array
    u16* XHs = (u16*)MH;  u16* XLs = XHs + SPE;   // X splits for knn (dead after knn)
    u16* QHs = (u16*)MH;  u16* QLs = QHs + SPE;   // Q splits (overwrite X splits)
    u16* KHs = (u16*)QT;  u16* KLs = KHs + SPE;   // QT region (after edgeconv)
    u16* VTH = (u16*)PT;  u16* VTL = VTH + SPE;   // PT region (after edgeconv)

    prep_kernel<<<256, 256, 0, stream>>>(w1, b1, g1, be1, w2, b2, g2, be2,
                                         wc1, bc1, cg, cbe, ws);
    transpose_fused_kernel<<<2*BATCH*NPTS, 128, 0, stream>>>(x, y, XT, YT, XX, XHs, XLs);
    knn8_kernel<<<dim3(NPTS/16, BATCH), 512, 0, stream>>>(XHs, XLs, XX, IDX);
    gemm_dual_kernel<<<BATCH*NPTS/8, 128, 0, stream>>>(XT, ws + OFF_W1SUM, ws + OFF_W1B,
                                                       ws + OFF_B1F, nullptr, PT, QT);
    edgeconv_kernel<<<BATCH*NPTS, 128, 0, stream>>>(PT, QT, IDX, ws + OFF_W2T,
                                                    ws + OFF_B2F, AGG);
    gemm_qkv_kernel<<<2*BATCH*NPTS/8, 128, 0, stream>>>(AGG, YT, wq, bq, wk, bk, wv, bv,
                                                        QHs, QLs, KHs, KLs, VTH, VTL);
    attn_mfma_kernel<<<dim3(64, NHEAD, BATCH), 256, 0, stream>>>(
        QHs, QLs, KHs, KLs, VTH, VTL, O0s, O1s, ML0, ML1);
    gemm_mh_kernel<<<BATCH*NPTS/8, 128, 0, stream>>>(O0s, O1s, ML0, ML1, wmh, bmh, MH);
    gemmT_kernel<256,256,true,false,false,true><<<BATCH*NPTS/8, 256, 0, stream>>>(
        AGG, MH, ws + OFF_WC1T, ws + OFF_BC1F, nullptr, TT);
    gemmT_kernel<256,128,false,true,true,false><<<BATCH*NPTS/8, 128, 0, stream>>>(
        TT, nullptr, wc2, bc2, AGG, out);
}